// Round 1
// baseline (639.800 us; speedup 1.0000x reference)
//
#include <hip/hip_runtime.h>
#include <math.h>

#define BB 16
#define NN 512
#define HH 8
#define EE 128
#define HE 1024
#define QSCALE 0.08838834764831845f
#define NEGV -1000000000.0f

// ---------------------------------------------------------------------------
// Kernel 1: fused QKV projection.  out[b,h,n,e] = x[b,n,:] @ W.T + bias
// (mask NOT applied here: masked k columns are forced to -1e9 in scores, and
//  masked q rows are zeroed by the final output mask multiply — identical
//  result to the reference for every surviving element.)
// Grid: (8192/64, 3072/64). 64x64 tile, 4x4 per thread, K=128 staged K-major.
// ---------------------------------------------------------------------------
__global__ __launch_bounds__(256) void k_qkv(
    const float* __restrict__ x,
    const float* __restrict__ Wq, const float* __restrict__ bq,
    const float* __restrict__ Wk, const float* __restrict__ bk,
    const float* __restrict__ Wv, const float* __restrict__ bv,
    float* __restrict__ Qh, float* __restrict__ Kh, float* __restrict__ Vh)
{
    __shared__ __align__(16) float Xs[EE][68];   // [k][m], pad 68 -> conflict-free b128 reads
    __shared__ __align__(16) float Ws[EE][68];   // [k][c]
    const int tid = threadIdx.x;
    const int tx = tid & 15, ty = tid >> 4;
    const int m0  = blockIdx.x * 64;
    const int c0g = blockIdx.y * 64;             // 0..3071 over {Wq|Wk|Wv}
    const int wsel = c0g >> 10;
    const int cc0  = c0g & 1023;
    const float* __restrict__ W    = (wsel == 0) ? Wq : (wsel == 1) ? Wk : Wv;
    const float* __restrict__ bias = (wsel == 0) ? bq : (wsel == 1) ? bk : bv;
    float* __restrict__ outp       = (wsel == 0) ? Qh : (wsel == 1) ? Kh : Vh;

    #pragma unroll
    for (int i = 0; i < 8; ++i) {
        const int f = i * 256 + tid;
        const int r = f >> 5;              // 0..63 tile row
        const int k4 = (f & 31) << 2;      // 0..124 k offset
        const float4 vx = *reinterpret_cast<const float4*>(x + (size_t)(m0 + r) * EE + k4);
        Xs[k4 + 0][r] = vx.x; Xs[k4 + 1][r] = vx.y; Xs[k4 + 2][r] = vx.z; Xs[k4 + 3][r] = vx.w;
        const float4 vw = *reinterpret_cast<const float4*>(W + (size_t)(cc0 + r) * EE + k4);
        Ws[k4 + 0][r] = vw.x; Ws[k4 + 1][r] = vw.y; Ws[k4 + 2][r] = vw.z; Ws[k4 + 3][r] = vw.w;
    }
    __syncthreads();

    float acc[4][4] = {};
    #pragma unroll 8
    for (int k = 0; k < EE; ++k) {
        const float4 a = *reinterpret_cast<const float4*>(&Xs[k][ty * 4]);
        const float4 w = *reinterpret_cast<const float4*>(&Ws[k][tx * 4]);
        const float av[4] = {a.x, a.y, a.z, a.w};
        const float wv[4] = {w.x, w.y, w.z, w.w};
        #pragma unroll
        for (int i2 = 0; i2 < 4; ++i2)
            #pragma unroll
            for (int j = 0; j < 4; ++j)
                acc[i2][j] = fmaf(av[i2], wv[j], acc[i2][j]);
    }

    const int b  = m0 >> 9;
    const int n0 = m0 & (NN - 1);
    const int h  = cc0 >> 7;
    const int e0 = (cc0 & 127) + tx * 4;
    const float4 b4 = *reinterpret_cast<const float4*>(bias + cc0 + tx * 4);
    #pragma unroll
    for (int i = 0; i < 4; ++i) {
        float4 o;
        o.x = acc[i][0] + b4.x; o.y = acc[i][1] + b4.y;
        o.z = acc[i][2] + b4.z; o.w = acc[i][3] + b4.w;
        *reinterpret_cast<float4*>(
            outp + ((size_t)(b * HH + h) * NN + n0 + ty * 4 + i) * EE + e0) = o;
    }
}

// ---------------------------------------------------------------------------
// Kernel 2: fused attention (flash-style, no SxS matrix in HBM).
// Block = (b, h, 64 q-rows), 256 threads (tx 0..15 = k/e cols, ty 0..15 = q rows).
// k-tiles of 64; online softmax with per-thread running (m,l) for 4 q rows,
// row reductions via shfl_xor over the 16-lane tx group; P through LDS for PV.
// Writes y_heads[b][n][h][e].
// ---------------------------------------------------------------------------
__global__ __launch_bounds__(256) void k_attn(
    const float* __restrict__ Qh, const float* __restrict__ Kh,
    const float* __restrict__ Vh, const float* __restrict__ dist,
    const float* __restrict__ mask, float* __restrict__ Yh)
{
    __shared__ __align__(16) float Qs[EE][68];   // [e][q]  34.8 KB
    __shared__ __align__(16) float Ks[EE][68];   // [e][k]  34.8 KB
    __shared__ __align__(16) float Vs[64][132];  // [k][e]  33.8 KB
    __shared__ __align__(16) float Ps[64][68];   // [k][q]  17.4 KB

    const int tid = threadIdx.x;
    const int tx = tid & 15, ty = tid >> 4;
    const int q0 = blockIdx.x * 64;
    const int h  = blockIdx.y;
    const int b  = blockIdx.z;

    const float* __restrict__ Qb = Qh + ((size_t)(b * HH + h) * NN + q0) * EE;
    const float* __restrict__ Kb = Kh + (size_t)(b * HH + h) * NN * EE;
    const float* __restrict__ Vb = Vh + (size_t)(b * HH + h) * NN * EE;

    #pragma unroll
    for (int i = 0; i < 8; ++i) {
        const int f = i * 256 + tid;
        const int r = f >> 5;
        const int k4 = (f & 31) << 2;
        const float4 v = *reinterpret_cast<const float4*>(Qb + (size_t)r * EE + k4);
        Qs[k4 + 0][r] = v.x; Qs[k4 + 1][r] = v.y; Qs[k4 + 2][r] = v.z; Qs[k4 + 3][r] = v.w;
    }

    float mq[4];
    #pragma unroll
    for (int i = 0; i < 4; ++i) mq[i] = mask[b * NN + q0 + ty * 4 + i];

    float mrun[4], lrun[4];
    float yacc[4][8] = {};
    #pragma unroll
    for (int i = 0; i < 4; ++i) { mrun[i] = -INFINITY; lrun[i] = 0.0f; }

    for (int kt = 0; kt < 8; ++kt) {
        const int k0 = kt * 64;
        #pragma unroll
        for (int i = 0; i < 8; ++i) {
            const int f = i * 256 + tid;
            const int r = f >> 5;
            const int k4 = (f & 31) << 2;
            const float4 kv = *reinterpret_cast<const float4*>(Kb + (size_t)(k0 + r) * EE + k4);
            Ks[k4 + 0][r] = kv.x; Ks[k4 + 1][r] = kv.y; Ks[k4 + 2][r] = kv.z; Ks[k4 + 3][r] = kv.w;
            const float4 vv = *reinterpret_cast<const float4*>(Vb + (size_t)(k0 + r) * EE + k4);
            *reinterpret_cast<float4*>(&Vs[r][k4]) = vv;
        }
        __syncthreads();

        // S = Q.K^T over e
        float s[4][4] = {};
        #pragma unroll 8
        for (int e = 0; e < EE; ++e) {
            const float4 a  = *reinterpret_cast<const float4*>(&Qs[e][ty * 4]);
            const float4 kk = *reinterpret_cast<const float4*>(&Ks[e][tx * 4]);
            const float av[4] = {a.x, a.y, a.z, a.w};
            const float kv2[4] = {kk.x, kk.y, kk.z, kk.w};
            #pragma unroll
            for (int i2 = 0; i2 < 4; ++i2)
                #pragma unroll
                for (int j = 0; j < 4; ++j)
                    s[i2][j] = fmaf(av[i2], kv2[j], s[i2][j]);
        }

        const float4 mk4 = *reinterpret_cast<const float4*>(mask + b * NN + k0 + tx * 4);
        const float mk[4] = {mk4.x, mk4.y, mk4.z, mk4.w};

        #pragma unroll
        for (int i = 0; i < 4; ++i) {
            const float4 d4 = *reinterpret_cast<const float4*>(
                dist + ((size_t)b * NN + q0 + ty * 4 + i) * NN + k0 + tx * 4);
            const float dd[4] = {d4.x, d4.y, d4.z, d4.w};
            #pragma unroll
            for (int j = 0; j < 4; ++j) {
                const bool live = (mq[i] != 0.0f) && (mk[j] != 0.0f);
                s[i][j] = live ? fmaf(s[i][j], QSCALE, dd[j]) : NEGV;
            }
        }

        // online softmax update (per q row; row lives on 16 tx lanes)
        #pragma unroll
        for (int i = 0; i < 4; ++i) {
            float tm = fmaxf(fmaxf(s[i][0], s[i][1]), fmaxf(s[i][2], s[i][3]));
            tm = fmaxf(tm, __shfl_xor(tm, 1));
            tm = fmaxf(tm, __shfl_xor(tm, 2));
            tm = fmaxf(tm, __shfl_xor(tm, 4));
            tm = fmaxf(tm, __shfl_xor(tm, 8));
            const float mn = fmaxf(mrun[i], tm);
            const float alpha = __expf(mrun[i] - mn);   // first tile: exp(-inf)=0
            mrun[i] = mn;
            float p[4];
            float rs = 0.0f;
            #pragma unroll
            for (int j = 0; j < 4; ++j) { p[j] = __expf(s[i][j] - mn); rs += p[j]; }
            rs += __shfl_xor(rs, 1);
            rs += __shfl_xor(rs, 2);
            rs += __shfl_xor(rs, 4);
            rs += __shfl_xor(rs, 8);
            lrun[i] = lrun[i] * alpha + rs;
            #pragma unroll
            for (int jj = 0; jj < 8; ++jj) yacc[i][jj] *= alpha;
            #pragma unroll
            for (int j = 0; j < 4; ++j) Ps[tx * 4 + j][ty * 4 + i] = p[j];
        }
        __syncthreads();

        // yacc += P.V   (thread e-cols: tx*4..+3 and 64+tx*4..+3 -> 2-way-free banks)
        #pragma unroll 8
        for (int k = 0; k < 64; ++k) {
            const float4 pp  = *reinterpret_cast<const float4*>(&Ps[k][ty * 4]);
            const float4 va  = *reinterpret_cast<const float4*>(&Vs[k][tx * 4]);
            const float4 vb2 = *reinterpret_cast<const float4*>(&Vs[k][64 + tx * 4]);
            const float pr[4]  = {pp.x, pp.y, pp.z, pp.w};
            const float vva[4] = {va.x, va.y, va.z, va.w};
            const float vvb[4] = {vb2.x, vb2.y, vb2.z, vb2.w};
            #pragma unroll
            for (int i2 = 0; i2 < 4; ++i2) {
                #pragma unroll
                for (int j = 0; j < 4; ++j) {
                    yacc[i2][j]     = fmaf(pr[i2], vva[j], yacc[i2][j]);
                    yacc[i2][4 + j] = fmaf(pr[i2], vvb[j], yacc[i2][4 + j]);
                }
            }
        }
        __syncthreads();   // before next tile overwrites Ks/Vs
    }

    #pragma unroll
    for (int i = 0; i < 4; ++i) {
        const float inv = 1.0f / lrun[i];   // lrun >= 1 always (max term exp(0)=1)
        const int q = q0 + ty * 4 + i;
        float* __restrict__ yo = Yh + ((size_t)(b * NN + q) * HH + h) * EE;
        float4 o;
        o.x = yacc[i][0] * inv; o.y = yacc[i][1] * inv;
        o.z = yacc[i][2] * inv; o.w = yacc[i][3] * inv;
        *reinterpret_cast<float4*>(yo + tx * 4) = o;
        o.x = yacc[i][4] * inv; o.y = yacc[i][5] * inv;
        o.z = yacc[i][6] * inv; o.w = yacc[i][7] * inv;
        *reinterpret_cast<float4*>(yo + 64 + tx * 4) = o;
    }
}

// ---------------------------------------------------------------------------
// Kernel 3: output projection. out[b,n,:] = (y_heads[b,n,:] @ Wo.T + bo) * mask
// M=8192, Nc=128, K=1024. 64x64 tiles, K-tiles of 64.
// ---------------------------------------------------------------------------
__global__ __launch_bounds__(256) void k_out(
    const float* __restrict__ Yh, const float* __restrict__ Wo,
    const float* __restrict__ bo, const float* __restrict__ mask,
    float* __restrict__ out)
{
    __shared__ __align__(16) float As[64][68];
    __shared__ __align__(16) float Bs[64][68];
    const int tid = threadIdx.x;
    const int tx = tid & 15, ty = tid >> 4;
    const int m0 = blockIdx.x * 64;
    const int c0 = blockIdx.y * 64;

    float acc[4][4] = {};
    for (int kt = 0; kt < 16; ++kt) {
        const int kk0 = kt * 64;
        #pragma unroll
        for (int i = 0; i < 4; ++i) {
            const int f = i * 256 + tid;
            const int r = f >> 4;
            const int k4 = (f & 15) << 2;
            const float4 a = *reinterpret_cast<const float4*>(Yh + (size_t)(m0 + r) * HE + kk0 + k4);
            As[k4 + 0][r] = a.x; As[k4 + 1][r] = a.y; As[k4 + 2][r] = a.z; As[k4 + 3][r] = a.w;
            const float4 w = *reinterpret_cast<const float4*>(Wo + (size_t)(c0 + r) * HE + kk0 + k4);
            Bs[k4 + 0][r] = w.x; Bs[k4 + 1][r] = w.y; Bs[k4 + 2][r] = w.z; Bs[k4 + 3][r] = w.w;
        }
        __syncthreads();
        #pragma unroll 8
        for (int k = 0; k < 64; ++k) {
            const float4 a = *reinterpret_cast<const float4*>(&As[k][ty * 4]);
            const float4 w = *reinterpret_cast<const float4*>(&Bs[k][tx * 4]);
            const float av[4] = {a.x, a.y, a.z, a.w};
            const float wv[4] = {w.x, w.y, w.z, w.w};
            #pragma unroll
            for (int i2 = 0; i2 < 4; ++i2)
                #pragma unroll
                for (int j = 0; j < 4; ++j)
                    acc[i2][j] = fmaf(av[i2], wv[j], acc[i2][j]);
        }
        __syncthreads();
    }

    const float4 b4 = *reinterpret_cast<const float4*>(bo + c0 + tx * 4);
    #pragma unroll
    for (int i = 0; i < 4; ++i) {
        const int m = m0 + ty * 4 + i;
        const int b = m >> 9;
        const int n = m & (NN - 1);
        const float mm = mask[b * NN + n];
        float4 o;
        o.x = (acc[i][0] + b4.x) * mm;
        o.y = (acc[i][1] + b4.y) * mm;
        o.z = (acc[i][2] + b4.z) * mm;
        o.w = (acc[i][3] + b4.w) * mm;
        *reinterpret_cast<float4*>(out + (size_t)m * EE + c0 + tx * 4) = o;
    }
}

// ---------------------------------------------------------------------------
extern "C" void kernel_launch(void* const* d_in, const int* in_sizes, int n_in,
                              void* d_out, int out_size, void* d_ws, size_t ws_size,
                              hipStream_t stream) {
    const float* x    = (const float*)d_in[0];
    const float* dist = (const float*)d_in[1];
    const float* mask = (const float*)d_in[2];
    const float* Wq   = (const float*)d_in[3];
    const float* bq   = (const float*)d_in[4];
    const float* Wk   = (const float*)d_in[5];
    const float* bk   = (const float*)d_in[6];
    const float* Wv   = (const float*)d_in[7];
    const float* bv   = (const float*)d_in[8];
    const float* Wo   = (const float*)d_in[9];
    const float* bo   = (const float*)d_in[10];
    float* out = (float*)d_out;

    const size_t SZ = (size_t)BB * HH * NN * EE;   // 8,388,608 floats per tensor
    if (ws_size < 4 * SZ * sizeof(float)) return;  // need 128 MB scratch
    float* ws = (float*)d_ws;
    float* Qh = ws;
    float* Kh = ws + SZ;
    float* Vh = ws + 2 * SZ;
    float* Yh = ws + 3 * SZ;                        // [b][n][h][e]

    k_qkv<<<dim3(128, 48), 256, 0, stream>>>(x, Wq, bq, Wk, bk, Wv, bv, Qh, Kh, Vh);
    k_attn<<<dim3(NN / 64, HH, BB), 256, 0, stream>>>(Qh, Kh, Vh, dist, mask, Yh);
    k_out<<<dim3(128, 2), 256, 0, stream>>>(Yh, Wo, bo, mask, out);
}

// Round 2
// 454.377 us; speedup vs baseline: 1.4081x; 1.4081x over previous
//
#include <hip/hip_runtime.h>
#include <math.h>

#define BB 16
#define NN 512
#define HH 8
#define EE 128
#define HE 1024
#define QSCALE 0.08838834764831845f
#define NEGV -1000000000.0f

typedef short bf16x8 __attribute__((ext_vector_type(8)));
typedef float f32x4 __attribute__((ext_vector_type(4)));

// round-to-nearest-even fp32 -> bf16 pair (hi + lo residual). v == hi + lo to ~2^-17 rel.
__device__ __forceinline__ void split2(float v, unsigned short &hi, unsigned short &lo) {
    union { float f; unsigned u; } a; a.f = v;
    const unsigned r = (a.u + 0x7FFFu + ((a.u >> 16) & 1u)) >> 16;
    hi = (unsigned short)r;
    union { unsigned u; float f; } hf; hf.u = r << 16;
    const float res = v - hf.f;
    union { float f; unsigned u; } c; c.f = res;
    const unsigned r2 = (c.u + 0x7FFFu + ((c.u >> 16) & 1u)) >> 16;
    lo = (unsigned short)r2;
}

// ---------------------------------------------------------------------------
// Kernel 1: fused QKV projection (fp32 VALU GEMM core, unchanged).
// NEW epilogue: writes bf16 hi/lo splits. Q,K as [b][h][n][e]; V transposed
// as [b][h][e][n] so the attention kernel's V B-fragments are contiguous.
// ---------------------------------------------------------------------------
__global__ __launch_bounds__(256) void k_qkv(
    const float* __restrict__ x,
    const float* __restrict__ Wq, const float* __restrict__ bq,
    const float* __restrict__ Wk, const float* __restrict__ bk,
    const float* __restrict__ Wv, const float* __restrict__ bv,
    unsigned short* __restrict__ Qhi, unsigned short* __restrict__ Qlo,
    unsigned short* __restrict__ Khi, unsigned short* __restrict__ Klo,
    unsigned short* __restrict__ VThi, unsigned short* __restrict__ VTlo)
{
    __shared__ __align__(16) float Xs[EE][68];
    __shared__ __align__(16) float Ws[EE][68];
    const int tid = threadIdx.x;
    const int tx = tid & 15, ty = tid >> 4;
    const int m0  = blockIdx.x * 64;
    const int c0g = blockIdx.y * 64;
    const int wsel = c0g >> 10;
    const int cc0  = c0g & 1023;
    const float* __restrict__ W    = (wsel == 0) ? Wq : (wsel == 1) ? Wk : Wv;
    const float* __restrict__ bias = (wsel == 0) ? bq : (wsel == 1) ? bk : bv;

    #pragma unroll
    for (int i = 0; i < 8; ++i) {
        const int f = i * 256 + tid;
        const int r = f >> 5;
        const int k4 = (f & 31) << 2;
        const float4 vx = *reinterpret_cast<const float4*>(x + (size_t)(m0 + r) * EE + k4);
        Xs[k4 + 0][r] = vx.x; Xs[k4 + 1][r] = vx.y; Xs[k4 + 2][r] = vx.z; Xs[k4 + 3][r] = vx.w;
        const float4 vw = *reinterpret_cast<const float4*>(W + (size_t)(cc0 + r) * EE + k4);
        Ws[k4 + 0][r] = vw.x; Ws[k4 + 1][r] = vw.y; Ws[k4 + 2][r] = vw.z; Ws[k4 + 3][r] = vw.w;
    }
    __syncthreads();

    float acc[4][4] = {};
    #pragma unroll 8
    for (int k = 0; k < EE; ++k) {
        const float4 a = *reinterpret_cast<const float4*>(&Xs[k][ty * 4]);
        const float4 w = *reinterpret_cast<const float4*>(&Ws[k][tx * 4]);
        const float av[4] = {a.x, a.y, a.z, a.w};
        const float wv[4] = {w.x, w.y, w.z, w.w};
        #pragma unroll
        for (int i2 = 0; i2 < 4; ++i2)
            #pragma unroll
            for (int j = 0; j < 4; ++j)
                acc[i2][j] = fmaf(av[i2], wv[j], acc[i2][j]);
    }

    const int b  = m0 >> 9;
    const int n0 = m0 & (NN - 1);
    const int h  = cc0 >> 7;
    const int bh = b * HH + h;
    const float4 b4 = *reinterpret_cast<const float4*>(bias + cc0 + tx * 4);
    const float bb[4] = {b4.x, b4.y, b4.z, b4.w};

    if (wsel < 2) {
        unsigned short* __restrict__ hp = (wsel == 0) ? Qhi : Khi;
        unsigned short* __restrict__ lp = (wsel == 0) ? Qlo : Klo;
        const int e0 = (cc0 & 127) + tx * 4;
        #pragma unroll
        for (int i = 0; i < 4; ++i) {
            unsigned short th[4], tl[4];
            #pragma unroll
            for (int j = 0; j < 4; ++j) split2(acc[i][j] + bb[j], th[j], tl[j]);
            const size_t off = ((size_t)bh * NN + n0 + ty * 4 + i) * EE + e0;
            *reinterpret_cast<ushort4*>(hp + off) = *reinterpret_cast<ushort4*>(th);
            *reinterpret_cast<ushort4*>(lp + off) = *reinterpret_cast<ushort4*>(tl);
        }
    } else {
        #pragma unroll
        for (int j = 0; j < 4; ++j) {
            const int e = (cc0 & 127) + tx * 4 + j;
            unsigned short th[4], tl[4];
            #pragma unroll
            for (int i = 0; i < 4; ++i) split2(acc[i][j] + bb[j], th[i], tl[i]);
            const size_t off = ((size_t)bh * EE + e) * NN + n0 + ty * 4;
            *reinterpret_cast<ushort4*>(VThi + off) = *reinterpret_cast<ushort4*>(th);
            *reinterpret_cast<ushort4*>(VTlo + off) = *reinterpret_cast<ushort4*>(tl);
        }
    }
}

// ---------------------------------------------------------------------------
// Kernel 2: fused attention via split-bf16 MFMA (fp32-accurate emulation).
// Block = (b, h, 128 q-rows), 4 waves x 32 rows. K-tiles of 64.
// S = Qhi.Khi + Qhi.Klo + Qlo.Khi (3x mfma_f32_16x16x32_bf16), online softmax
// in registers, P split+packed to LDS (reusing K buffer), PV same 3-term MFMA.
// LDS 64 KB -> 2 blocks/CU. XOR swizzle on all tiles (conflict-free b128).
// ---------------------------------------------------------------------------
__global__ __launch_bounds__(256, 2) void k_attn(
    const unsigned short* __restrict__ Qhi, const unsigned short* __restrict__ Qlo,
    const unsigned short* __restrict__ Khi_g, const unsigned short* __restrict__ Klo_g,
    const unsigned short* __restrict__ VThi_g, const unsigned short* __restrict__ VTlo_g,
    const float* __restrict__ dist, const float* __restrict__ mask,
    float* __restrict__ Yh)
{
    __shared__ __align__(16) unsigned char smem[65536];
    unsigned short* sKhi = (unsigned short*)smem;            // [64 n][128 e] swz
    unsigned short* sKlo = (unsigned short*)(smem + 16384);
    unsigned short* sVhi = (unsigned short*)(smem + 32768);  // [128 e][64 n] swz
    unsigned short* sVlo = (unsigned short*)(smem + 49152);
    unsigned* sP = (unsigned*)smem;                          // [128 q][64 k] u32, overlays K

    const int tid = threadIdx.x;
    const int w  = tid >> 6;
    const int l  = tid & 63;
    const int g  = l >> 4;
    const int ln = l & 15;
    const int h = blockIdx.y, b = blockIdx.z;
    const int q0 = blockIdx.x * 128;
    const int bh = b * HH + h;
    const size_t baseQ = (size_t)bh * NN * EE;
    const size_t baseV = (size_t)bh * EE * NN;

    // Q fragments in registers (row = ln within stripe; logical e = 32ks+8g+i)
    bf16x8 qa_hi[2][4], qa_lo[2][4];
    #pragma unroll
    for (int s = 0; s < 2; ++s)
        #pragma unroll
        for (int ks = 0; ks < 4; ++ks) {
            const size_t qoff = baseQ + (size_t)(q0 + w * 32 + s * 16 + ln) * EE + ks * 32 + g * 8;
            qa_hi[s][ks] = *reinterpret_cast<const bf16x8*>(Qhi + qoff);
            qa_lo[s][ks] = *reinterpret_cast<const bf16x8*>(Qlo + qoff);
        }

    float mq[2][4];
    #pragma unroll
    for (int s = 0; s < 2; ++s)
        #pragma unroll
        for (int r = 0; r < 4; ++r)
            mq[s][r] = mask[b * NN + q0 + w * 32 + s * 16 + g * 4 + r];

    float mrun[2][4], lrun[2][4];
    f32x4 yacc[2][8];
    const f32x4 fz = {0.f, 0.f, 0.f, 0.f};
    #pragma unroll
    for (int s = 0; s < 2; ++s) {
        #pragma unroll
        for (int r = 0; r < 4; ++r) { mrun[s][r] = -INFINITY; lrun[s][r] = 0.f; }
        #pragma unroll
        for (int et = 0; et < 8; ++et) yacc[s][et] = fz;
    }

    for (int kt = 0; kt < 8; ++kt) {
        const int k0 = kt * 64;
        // ---- stage K tile [64][128] and VT tile [128][64] (hi+lo), swizzled ----
        #pragma unroll
        for (int i = 0; i < 4; ++i) {
            const int f = i * 256 + tid;            // 0..1023
            const int n = f >> 4, c = f & 15;
            const uint4 vh = *reinterpret_cast<const uint4*>(Khi_g + baseQ + (size_t)(k0 + n) * EE + c * 8);
            const uint4 vl = *reinterpret_cast<const uint4*>(Klo_g + baseQ + (size_t)(k0 + n) * EE + c * 8);
            const int offK = n * 256 + ((c * 16) ^ ((n & 7) << 4));
            *reinterpret_cast<uint4*>((char*)sKhi + offK) = vh;
            *reinterpret_cast<uint4*>((char*)sKlo + offK) = vl;
            const int e = f >> 3, c2 = f & 7;
            const uint4 wh = *reinterpret_cast<const uint4*>(VThi_g + baseV + (size_t)e * NN + k0 + c2 * 8);
            const uint4 wl = *reinterpret_cast<const uint4*>(VTlo_g + baseV + (size_t)e * NN + k0 + c2 * 8);
            const int offV = e * 128 + ((c2 * 16) ^ ((e & 7) << 4));
            *reinterpret_cast<uint4*>((char*)sVhi + offV) = wh;
            *reinterpret_cast<uint4*>((char*)sVlo + offV) = wl;
        }
        __syncthreads();

        float mk[4];
        #pragma unroll
        for (int t = 0; t < 4; ++t) mk[t] = mask[b * NN + k0 + t * 16 + ln];

        // ---- S = Q.K^T (3-term split) ----
        f32x4 sacc[2][4];
        #pragma unroll
        for (int s = 0; s < 2; ++s)
            #pragma unroll
            for (int t = 0; t < 4; ++t) sacc[s][t] = fz;

        #pragma unroll
        for (int ks = 0; ks < 4; ++ks) {
            #pragma unroll
            for (int t = 0; t < 4; ++t) {
                const int row = t * 16 + ln;
                const int off = row * 256 + (((ks * 64) + g * 16) ^ ((row & 7) << 4));
                const bf16x8 kbh = *reinterpret_cast<const bf16x8*>((char*)sKhi + off);
                const bf16x8 kbl = *reinterpret_cast<const bf16x8*>((char*)sKlo + off);
                #pragma unroll
                for (int s = 0; s < 2; ++s) {
                    sacc[s][t] = __builtin_amdgcn_mfma_f32_16x16x32_bf16(qa_hi[s][ks], kbh, sacc[s][t], 0, 0, 0);
                    sacc[s][t] = __builtin_amdgcn_mfma_f32_16x16x32_bf16(qa_lo[s][ks], kbh, sacc[s][t], 0, 0, 0);
                    sacc[s][t] = __builtin_amdgcn_mfma_f32_16x16x32_bf16(qa_hi[s][ks], kbl, sacc[s][t], 0, 0, 0);
                }
            }
        }

        // dist loads (latency hides under the barrier drain)
        float dv[2][4][4];
        #pragma unroll
        for (int s = 0; s < 2; ++s)
            #pragma unroll
            for (int r = 0; r < 4; ++r) {
                const size_t drow = ((size_t)b * NN + q0 + w * 32 + s * 16 + g * 4 + r) * NN + k0;
                #pragma unroll
                for (int t = 0; t < 4; ++t) dv[s][t][r] = dist[drow + t * 16 + ln];
            }
        __syncthreads();   // all waves done reading K LDS -> safe to overlay P

        // ---- online softmax + P write ----
        #pragma unroll
        for (int s = 0; s < 2; ++s) {
            float alpha[4], mn[4];
            #pragma unroll
            for (int r = 0; r < 4; ++r) {
                float sv[4];
                #pragma unroll
                for (int t = 0; t < 4; ++t) {
                    const bool live = (mq[s][r] != 0.f) && (mk[t] != 0.f);
                    sv[t] = live ? fmaf(sacc[s][t][r], QSCALE, dv[s][t][r]) : NEGV;
                    sacc[s][t][r] = sv[t];
                }
                float tm = fmaxf(fmaxf(sv[0], sv[1]), fmaxf(sv[2], sv[3]));
                tm = fmaxf(tm, __shfl_xor(tm, 1));
                tm = fmaxf(tm, __shfl_xor(tm, 2));
                tm = fmaxf(tm, __shfl_xor(tm, 4));
                tm = fmaxf(tm, __shfl_xor(tm, 8));
                const float m2 = fmaxf(mrun[s][r], tm);
                alpha[r] = __expf(mrun[s][r] - m2);
                mrun[s][r] = m2; mn[r] = m2;
            }
            #pragma unroll
            for (int r = 0; r < 4; ++r) {
                float p[4], rs = 0.f;
                #pragma unroll
                for (int t = 0; t < 4; ++t) { p[t] = __expf(sacc[s][t][r] - mn[r]); rs += p[t]; }
                rs += __shfl_xor(rs, 1); rs += __shfl_xor(rs, 2);
                rs += __shfl_xor(rs, 4); rs += __shfl_xor(rs, 8);
                lrun[s][r] = lrun[s][r] * alpha[r] + rs;
                const int q = w * 32 + s * 16 + g * 4 + r;
                #pragma unroll
                for (int t = 0; t < 4; ++t) {
                    unsigned short ph, pl;
                    split2(p[t], ph, pl);
                    const int k = t * 16 + ln;
                    const int off = q * 256 + ((k * 4) ^ ((q & 7) << 4));
                    *reinterpret_cast<unsigned*>((char*)sP + off) = ((unsigned)ph << 16) | pl;
                }
                #pragma unroll
                for (int et = 0; et < 8; ++et) yacc[s][et][r] *= alpha[r];
            }
        }
        __syncthreads();   // P visible

        // ---- Y += P.V (3-term split) ----
        #pragma unroll
        for (int ks = 0; ks < 2; ++ks) {
            bf16x8 pah[2], pal[2];
            #pragma unroll
            for (int s = 0; s < 2; ++s) {
                const int q = w * 32 + s * 16 + ln;
                const int swz = (q & 7) << 4;
                const int colb = ks * 128 + g * 32;
                const uint4 r0 = *reinterpret_cast<const uint4*>((char*)sP + q * 256 + (colb ^ swz));
                const uint4 r1 = *reinterpret_cast<const uint4*>((char*)sP + q * 256 + ((colb + 16) ^ swz));
                const unsigned wrd[8] = {r0.x, r0.y, r0.z, r0.w, r1.x, r1.y, r1.z, r1.w};
                unsigned hh[4], llw[4];
                #pragma unroll
                for (int d = 0; d < 4; ++d) {
                    hh[d]  = __builtin_amdgcn_perm(wrd[2 * d + 1], wrd[2 * d], 0x07060302u);
                    llw[d] = __builtin_amdgcn_perm(wrd[2 * d + 1], wrd[2 * d], 0x05040100u);
                }
                typedef unsigned u32x4 __attribute__((ext_vector_type(4)));
                u32x4 th = {hh[0], hh[1], hh[2], hh[3]};
                u32x4 tl = {llw[0], llw[1], llw[2], llw[3]};
                pah[s] = __builtin_bit_cast(bf16x8, th);
                pal[s] = __builtin_bit_cast(bf16x8, tl);
            }
            #pragma unroll
            for (int et = 0; et < 8; ++et) {
                const int e = et * 16 + ln;
                const int off = e * 128 + (((ks * 64) + g * 16) ^ ((e & 7) << 4));
                const bf16x8 vbh = *reinterpret_cast<const bf16x8*>((char*)sVhi + off);
                const bf16x8 vbl = *reinterpret_cast<const bf16x8*>((char*)sVlo + off);
                #pragma unroll
                for (int s = 0; s < 2; ++s) {
                    yacc[s][et] = __builtin_amdgcn_mfma_f32_16x16x32_bf16(pah[s], vbh, yacc[s][et], 0, 0, 0);
                    yacc[s][et] = __builtin_amdgcn_mfma_f32_16x16x32_bf16(pal[s], vbh, yacc[s][et], 0, 0, 0);
                    yacc[s][et] = __builtin_amdgcn_mfma_f32_16x16x32_bf16(pah[s], vbl, yacc[s][et], 0, 0, 0);
                }
            }
        }
        __syncthreads();   // done with P / V before next tile staging
    }

    // ---- epilogue: y / l -> Yh[b][n][h][e] fp32 ----
    #pragma unroll
    for (int s = 0; s < 2; ++s) {
        float inv[4];
        #pragma unroll
        for (int r = 0; r < 4; ++r) inv[r] = 1.0f / lrun[s][r];
        #pragma unroll
        for (int et = 0; et < 8; ++et) {
            #pragma unroll
            for (int r = 0; r < 4; ++r) {
                const int q = q0 + w * 32 + s * 16 + g * 4 + r;
                Yh[((size_t)(b * NN + q)) * HE + h * EE + et * 16 + ln] = yacc[s][et][r] * inv[r];
            }
        }
    }
}

// ---------------------------------------------------------------------------
// Kernel 3: output projection (unchanged fp32).
// ---------------------------------------------------------------------------
__global__ __launch_bounds__(256) void k_out(
    const float* __restrict__ Yh, const float* __restrict__ Wo,
    const float* __restrict__ bo, const float* __restrict__ mask,
    float* __restrict__ out)
{
    __shared__ __align__(16) float As[64][68];
    __shared__ __align__(16) float Bs[64][68];
    const int tid = threadIdx.x;
    const int tx = tid & 15, ty = tid >> 4;
    const int m0 = blockIdx.x * 64;
    const int c0 = blockIdx.y * 64;

    float acc[4][4] = {};
    for (int kt = 0; kt < 16; ++kt) {
        const int kk0 = kt * 64;
        #pragma unroll
        for (int i = 0; i < 4; ++i) {
            const int f = i * 256 + tid;
            const int r = f >> 4;
            const int k4 = (f & 15) << 2;
            const float4 a = *reinterpret_cast<const float4*>(Yh + (size_t)(m0 + r) * HE + kk0 + k4);
            As[k4 + 0][r] = a.x; As[k4 + 1][r] = a.y; As[k4 + 2][r] = a.z; As[k4 + 3][r] = a.w;
            const float4 ww = *reinterpret_cast<const float4*>(Wo + (size_t)(c0 + r) * HE + kk0 + k4);
            Bs[k4 + 0][r] = ww.x; Bs[k4 + 1][r] = ww.y; Bs[k4 + 2][r] = ww.z; Bs[k4 + 3][r] = ww.w;
        }
        __syncthreads();
        #pragma unroll 8
        for (int k = 0; k < 64; ++k) {
            const float4 a = *reinterpret_cast<const float4*>(&As[k][ty * 4]);
            const float4 ww = *reinterpret_cast<const float4*>(&Bs[k][tx * 4]);
            const float av[4] = {a.x, a.y, a.z, a.w};
            const float wv[4] = {ww.x, ww.y, ww.z, ww.w};
            #pragma unroll
            for (int i2 = 0; i2 < 4; ++i2)
                #pragma unroll
                for (int j = 0; j < 4; ++j)
                    acc[i2][j] = fmaf(av[i2], wv[j], acc[i2][j]);
        }
        __syncthreads();
    }

    const float4 b4 = *reinterpret_cast<const float4*>(bo + c0 + tx * 4);
    #pragma unroll
    for (int i = 0; i < 4; ++i) {
        const int m = m0 + ty * 4 + i;
        const int b = m >> 9;
        const int n = m & (NN - 1);
        const float mm = mask[b * NN + n];
        float4 o;
        o.x = (acc[i][0] + b4.x) * mm;
        o.y = (acc[i][1] + b4.y) * mm;
        o.z = (acc[i][2] + b4.z) * mm;
        o.w = (acc[i][3] + b4.w) * mm;
        *reinterpret_cast<float4*>(out + (size_t)m * EE + c0 + tx * 4) = o;
    }
}

// ---------------------------------------------------------------------------
extern "C" void kernel_launch(void* const* d_in, const int* in_sizes, int n_in,
                              void* d_out, int out_size, void* d_ws, size_t ws_size,
                              hipStream_t stream) {
    const float* x    = (const float*)d_in[0];
    const float* dist = (const float*)d_in[1];
    const float* mask = (const float*)d_in[2];
    const float* Wq   = (const float*)d_in[3];
    const float* bq   = (const float*)d_in[4];
    const float* Wk   = (const float*)d_in[5];
    const float* bk   = (const float*)d_in[6];
    const float* Wv   = (const float*)d_in[7];
    const float* bv   = (const float*)d_in[8];
    const float* Wo   = (const float*)d_in[9];
    const float* bo   = (const float*)d_in[10];
    float* out = (float*)d_out;

    const size_t SZ = (size_t)BB * HH * NN * EE;     // 8,388,608 elems per tensor
    if (ws_size < SZ * 16) return;                   // 6 bf16 splits + Yh fp32 = 134 MB
    unsigned short* Qhi  = (unsigned short*)d_ws;
    unsigned short* Qlo  = Qhi + SZ;
    unsigned short* Khi  = Qhi + 2 * SZ;
    unsigned short* Klo  = Qhi + 3 * SZ;
    unsigned short* VThi = Qhi + 4 * SZ;
    unsigned short* VTlo = Qhi + 5 * SZ;
    float* Yh = (float*)(Qhi + 6 * SZ);              // [b][n][h][e] fp32

    k_qkv<<<dim3(128, 48), 256, 0, stream>>>(x, Wq, bq, Wk, bk, Wv, bv,
                                             Qhi, Qlo, Khi, Klo, VThi, VTlo);
    k_attn<<<dim3(NN / 128, HH, BB), 256, 0, stream>>>(Qhi, Qlo, Khi, Klo, VThi, VTlo,
                                                       dist, mask, Yh);
    k_out<<<dim3(128, 2), 256, 0, stream>>>(Yh, Wo, bo, mask, out);
}

// Round 3
// 342.661 us; speedup vs baseline: 1.8671x; 1.3260x over previous
//
#include <hip/hip_runtime.h>
#include <math.h>

#define BB 16
#define NN 512
#define HH 8
#define EE 128
#define HE 1024
#define QSCALE 0.08838834764831845f
#define NEGV -1000000000.0f

typedef short bf16x8 __attribute__((ext_vector_type(8)));
typedef float f32x4 __attribute__((ext_vector_type(4)));
typedef unsigned u32x4 __attribute__((ext_vector_type(4)));

// round-to-nearest-even fp32 -> bf16 pair (hi + lo residual). v ~= hi + lo to ~2^-17 rel.
__device__ __forceinline__ void split2(float v, unsigned short &hi, unsigned short &lo) {
    union { float f; unsigned u; } a; a.f = v;
    const unsigned r = (a.u + 0x7FFFu + ((a.u >> 16) & 1u)) >> 16;
    hi = (unsigned short)r;
    union { unsigned u; float f; } hf; hf.u = r << 16;
    const float res = v - hf.f;
    union { float f; unsigned u; } c; c.f = res;
    const unsigned r2 = (c.u + 0x7FFFu + ((c.u >> 16) & 1u)) >> 16;
    lo = (unsigned short)r2;
}

// ---------------------------------------------------------------------------
// k_split: x[1048576] -> xhi/xlo; Wq|Wk|Wv (3x131072) -> wchi/wclo [3072][128]
// ---------------------------------------------------------------------------
__global__ __launch_bounds__(256) void k_split(
    const float* __restrict__ x,
    const float* __restrict__ Wq, const float* __restrict__ Wk, const float* __restrict__ Wv,
    unsigned short* __restrict__ xhi, unsigned short* __restrict__ xlo,
    unsigned short* __restrict__ wchi, unsigned short* __restrict__ wclo)
{
    const int id = blockIdx.x * 256 + threadIdx.x;
    const int i4 = id * 4;
    const float* src;
    unsigned short *dh, *dl;
    int off;
    if (i4 < 1048576) { src = x; off = i4; dh = xhi + i4; dl = xlo + i4; }
    else {
        const int j = i4 - 1048576;
        const int msel = j >> 17;
        off = j & 131071;
        src = (msel == 0) ? Wq : (msel == 1) ? Wk : Wv;
        dh = wchi + j; dl = wclo + j;
    }
    const float4 v = *reinterpret_cast<const float4*>(src + off);
    unsigned short h[4], l[4];
    split2(v.x, h[0], l[0]); split2(v.y, h[1], l[1]);
    split2(v.z, h[2], l[2]); split2(v.w, h[3], l[3]);
    *reinterpret_cast<ushort4*>(dh) = *reinterpret_cast<ushort4*>(h);
    *reinterpret_cast<ushort4*>(dl) = *reinterpret_cast<ushort4*>(l);
}

// k_split_wo: Wo [128][1024] fp32 -> wohi/wolo (runs after k_attn, into dead QKV region)
__global__ __launch_bounds__(256) void k_split_wo(
    const float* __restrict__ Wo,
    unsigned short* __restrict__ wohi, unsigned short* __restrict__ wolo)
{
    const int i4 = (blockIdx.x * 256 + threadIdx.x) * 4;
    const float4 v = *reinterpret_cast<const float4*>(Wo + i4);
    unsigned short h[4], l[4];
    split2(v.x, h[0], l[0]); split2(v.y, h[1], l[1]);
    split2(v.z, h[2], l[2]); split2(v.w, h[3], l[3]);
    *reinterpret_cast<ushort4*>(wohi + i4) = *reinterpret_cast<ushort4*>(h);
    *reinterpret_cast<ushort4*>(wolo + i4) = *reinterpret_cast<ushort4*>(l);
}

// ---------------------------------------------------------------------------
// k_qkv: 3-term split-bf16 MFMA GEMM. M=8192, C=3072 (Wq|Wk|Wv), K=128.
// 128x128 tiles, 4 waves (2x2 of 64x64), K-steps of 64 via LDS (swizzled).
// Epilogue: +bias, split2 -> Q/K [bh][n][e]; V transposed via LDS -> [bh][e][n].
// ---------------------------------------------------------------------------
__global__ __launch_bounds__(256, 2) void k_qkv(
    const unsigned short* __restrict__ xhi, const unsigned short* __restrict__ xlo,
    const unsigned short* __restrict__ wchi, const unsigned short* __restrict__ wclo,
    const float* __restrict__ bq, const float* __restrict__ bk, const float* __restrict__ bv,
    unsigned short* __restrict__ Qhi, unsigned short* __restrict__ Qlo,
    unsigned short* __restrict__ Khi, unsigned short* __restrict__ Klo,
    unsigned short* __restrict__ VThi, unsigned short* __restrict__ VTlo)
{
    __shared__ __align__(16) unsigned char smem[65536];
    // planes: sAhi 0, sAlo 16K, sBhi 32K, sBlo 48K. each [128 rows][64 k] bf16,
    // row stride 128B, byte swizzle ^((row&7)<<4).
    const int tid = threadIdx.x;
    const int w = tid >> 6, l = tid & 63, g = l >> 4, ln = l & 15;
    const int wm = w >> 1, wc = w & 1;
    const int m0  = blockIdx.x * 128;
    const int c0g = blockIdx.y * 128;
    const int wsel = c0g >> 10;
    const int cc0  = c0g & 1023;           // multiple of 128 within matrix
    const float* __restrict__ bias = (wsel == 0) ? bq : (wsel == 1) ? bk : bv;

    f32x4 acc[4][4];
    const f32x4 fz = {0.f, 0.f, 0.f, 0.f};
    #pragma unroll
    for (int i = 0; i < 4; ++i)
        #pragma unroll
        for (int j = 0; j < 4; ++j) acc[i][j] = fz;

    for (int kt = 0; kt < 2; ++kt) {
        const int k0 = kt * 64;
        if (kt) __syncthreads();
        #pragma unroll
        for (int i = 0; i < 4; ++i) {
            const int f = i * 256 + tid;       // 0..1023
            const int row = f >> 3, c8 = f & 7;
            const int off = row * 128 + ((c8 * 16) ^ ((row & 7) << 4));
            *reinterpret_cast<uint4*>(smem + off) =
                *reinterpret_cast<const uint4*>(xhi + (size_t)(m0 + row) * EE + k0 + c8 * 8);
            *reinterpret_cast<uint4*>(smem + 16384 + off) =
                *reinterpret_cast<const uint4*>(xlo + (size_t)(m0 + row) * EE + k0 + c8 * 8);
            *reinterpret_cast<uint4*>(smem + 32768 + off) =
                *reinterpret_cast<const uint4*>(wchi + (size_t)(c0g + row) * EE + k0 + c8 * 8);
            *reinterpret_cast<uint4*>(smem + 49152 + off) =
                *reinterpret_cast<const uint4*>(wclo + (size_t)(c0g + row) * EE + k0 + c8 * 8);
        }
        __syncthreads();

        #pragma unroll
        for (int ks = 0; ks < 2; ++ks) {
            bf16x8 ah[4], al[4], bh[4], bl[4];
            #pragma unroll
            for (int i = 0; i < 4; ++i) {
                const int rm = wm * 64 + i * 16 + ln;
                const int off = rm * 128 + (((ks * 64) + g * 16) ^ ((rm & 7) << 4));
                ah[i] = *reinterpret_cast<const bf16x8*>(smem + off);
                al[i] = *reinterpret_cast<const bf16x8*>(smem + 16384 + off);
            }
            #pragma unroll
            for (int j = 0; j < 4; ++j) {
                const int rc = wc * 64 + j * 16 + ln;
                const int off = rc * 128 + (((ks * 64) + g * 16) ^ ((rc & 7) << 4));
                bh[j] = *reinterpret_cast<const bf16x8*>(smem + 32768 + off);
                bl[j] = *reinterpret_cast<const bf16x8*>(smem + 49152 + off);
            }
            #pragma unroll
            for (int i = 0; i < 4; ++i)
                #pragma unroll
                for (int j = 0; j < 4; ++j) {
                    acc[i][j] = __builtin_amdgcn_mfma_f32_16x16x32_bf16(ah[i], bl[j], acc[i][j], 0, 0, 0);
                    acc[i][j] = __builtin_amdgcn_mfma_f32_16x16x32_bf16(al[i], bh[j], acc[i][j], 0, 0, 0);
                    acc[i][j] = __builtin_amdgcn_mfma_f32_16x16x32_bf16(ah[i], bh[j], acc[i][j], 0, 0, 0);
                }
        }
    }

    const int b  = m0 >> 9;
    const int h  = cc0 >> 7;
    const int bh_ = b * HH + h;
    const int nb = (m0 & (NN - 1));

    if (wsel < 2) {
        unsigned short* __restrict__ hp = (wsel == 0) ? Qhi : Khi;
        unsigned short* __restrict__ lp = (wsel == 0) ? Qlo : Klo;
        #pragma unroll
        for (int j = 0; j < 4; ++j) {
            const int clocal = wc * 64 + j * 16 + ln;
            const float bj = bias[cc0 + clocal];
            #pragma unroll
            for (int i = 0; i < 4; ++i) {
                #pragma unroll
                for (int r = 0; r < 4; ++r) {
                    const int n = nb + wm * 64 + i * 16 + g * 4 + r;
                    unsigned short th, tl;
                    split2(acc[i][j][r] + bj, th, tl);
                    const size_t o = ((size_t)bh_ * NN + n) * EE + clocal;
                    hp[o] = th; lp[o] = tl;
                }
            }
        }
    } else {
        // V: pack (hi<<16|lo) into LDS [c 128][m 128] u32 (swizzled), then
        // coalesced transposed 16B stores to VT [bh][e][n].
        __syncthreads();
        unsigned* sp = (unsigned*)smem;
        #pragma unroll
        for (int j = 0; j < 4; ++j) {
            const int clocal = wc * 64 + j * 16 + ln;
            const float bj = bias[cc0 + clocal];
            #pragma unroll
            for (int i = 0; i < 4; ++i) {
                #pragma unroll
                for (int r = 0; r < 4; ++r) {
                    const int mlocal = wm * 64 + i * 16 + g * 4 + r;
                    unsigned short th, tl;
                    split2(acc[i][j][r] + bj, th, tl);
                    const int off = clocal * 512 + ((mlocal * 4) ^ ((clocal & 7) << 4));
                    *reinterpret_cast<unsigned*>((char*)sp + off) = ((unsigned)th << 16) | tl;
                }
            }
        }
        __syncthreads();
        const int eloc = tid >> 1;
        const int nh0 = (tid & 1) * 64;
        #pragma unroll
        for (int u = 0; u < 8; ++u) {
            const int nloc = nh0 + u * 8;
            const int sw = (eloc & 7) << 4;
            const u32x4 q0 = *reinterpret_cast<const u32x4*>((char*)sp + eloc * 512 + ((nloc * 4) ^ sw));
            const u32x4 q1 = *reinterpret_cast<const u32x4*>((char*)sp + eloc * 512 + (((nloc + 4) * 4) ^ sw));
            unsigned short hhv[8], llv[8];
            #pragma unroll
            for (int t = 0; t < 4; ++t) {
                hhv[t] = (unsigned short)(q0[t] >> 16); llv[t] = (unsigned short)(q0[t] & 0xffff);
                hhv[4 + t] = (unsigned short)(q1[t] >> 16); llv[4 + t] = (unsigned short)(q1[t] & 0xffff);
            }
            const size_t o = ((size_t)bh_ * EE + eloc) * NN + nb + nloc;
            *reinterpret_cast<uint4*>(VThi + o) = *reinterpret_cast<uint4*>(hhv);
            *reinterpret_cast<uint4*>(VTlo + o) = *reinterpret_cast<uint4*>(llv);
        }
    }
}

// ---------------------------------------------------------------------------
// k_attn: unchanged core from R2 (split-bf16 MFMA flash attention).
// Changes: grid lin%8==h (K/V L2 reuse), epilogue writes Y bf16 hi/lo.
// ---------------------------------------------------------------------------
__global__ __launch_bounds__(256, 2) void k_attn(
    const unsigned short* __restrict__ Qhi, const unsigned short* __restrict__ Qlo,
    const unsigned short* __restrict__ Khi_g, const unsigned short* __restrict__ Klo_g,
    const unsigned short* __restrict__ VThi_g, const unsigned short* __restrict__ VTlo_g,
    const float* __restrict__ dist, const float* __restrict__ mask,
    unsigned short* __restrict__ Yhi, unsigned short* __restrict__ Ylo)
{
    __shared__ __align__(16) unsigned char smem[65536];
    unsigned short* sKhi = (unsigned short*)smem;            // [64 n][128 e] swz
    unsigned short* sKlo = (unsigned short*)(smem + 16384);
    unsigned short* sVhi = (unsigned short*)(smem + 32768);  // [128 e][64 n] swz
    unsigned short* sVlo = (unsigned short*)(smem + 49152);
    unsigned* sP = (unsigned*)smem;                          // [128 q][64 k] u32, overlays K

    const int tid = threadIdx.x;
    const int w  = tid >> 6;
    const int l  = tid & 63;
    const int g  = l >> 4;
    const int ln = l & 15;
    const int h  = blockIdx.x;       // fastest dim -> XCD = h : K/V reused across q-blocks
    const int qb = blockIdx.y;
    const int b  = blockIdx.z;
    const int q0 = qb * 128;
    const int bh = b * HH + h;
    const size_t baseQ = (size_t)bh * NN * EE;
    const size_t baseV = (size_t)bh * EE * NN;

    bf16x8 qa_hi[2][4], qa_lo[2][4];
    #pragma unroll
    for (int s = 0; s < 2; ++s)
        #pragma unroll
        for (int ks = 0; ks < 4; ++ks) {
            const size_t qoff = baseQ + (size_t)(q0 + w * 32 + s * 16 + ln) * EE + ks * 32 + g * 8;
            qa_hi[s][ks] = *reinterpret_cast<const bf16x8*>(Qhi + qoff);
            qa_lo[s][ks] = *reinterpret_cast<const bf16x8*>(Qlo + qoff);
        }

    float mq[2][4];
    #pragma unroll
    for (int s = 0; s < 2; ++s)
        #pragma unroll
        for (int r = 0; r < 4; ++r)
            mq[s][r] = mask[b * NN + q0 + w * 32 + s * 16 + g * 4 + r];

    float mrun[2][4], lrun[2][4];
    f32x4 yacc[2][8];
    const f32x4 fz = {0.f, 0.f, 0.f, 0.f};
    #pragma unroll
    for (int s = 0; s < 2; ++s) {
        #pragma unroll
        for (int r = 0; r < 4; ++r) { mrun[s][r] = -INFINITY; lrun[s][r] = 0.f; }
        #pragma unroll
        for (int et = 0; et < 8; ++et) yacc[s][et] = fz;
    }

    for (int kt = 0; kt < 8; ++kt) {
        const int k0 = kt * 64;
        #pragma unroll
        for (int i = 0; i < 4; ++i) {
            const int f = i * 256 + tid;
            const int n = f >> 4, c = f & 15;
            const uint4 vh = *reinterpret_cast<const uint4*>(Khi_g + baseQ + (size_t)(k0 + n) * EE + c * 8);
            const uint4 vl = *reinterpret_cast<const uint4*>(Klo_g + baseQ + (size_t)(k0 + n) * EE + c * 8);
            const int offK = n * 256 + ((c * 16) ^ ((n & 7) << 4));
            *reinterpret_cast<uint4*>((char*)sKhi + offK) = vh;
            *reinterpret_cast<uint4*>((char*)sKlo + offK) = vl;
            const int e = f >> 3, c2 = f & 7;
            const uint4 wh = *reinterpret_cast<const uint4*>(VThi_g + baseV + (size_t)e * NN + k0 + c2 * 8);
            const uint4 wl = *reinterpret_cast<const uint4*>(VTlo_g + baseV + (size_t)e * NN + k0 + c2 * 8);
            const int offV = e * 128 + ((c2 * 16) ^ ((e & 7) << 4));
            *reinterpret_cast<uint4*>((char*)sVhi + offV) = wh;
            *reinterpret_cast<uint4*>((char*)sVlo + offV) = wl;
        }
        __syncthreads();

        float mk[4];
        #pragma unroll
        for (int t = 0; t < 4; ++t) mk[t] = mask[b * NN + k0 + t * 16 + ln];

        f32x4 sacc[2][4];
        #pragma unroll
        for (int s = 0; s < 2; ++s)
            #pragma unroll
            for (int t = 0; t < 4; ++t) sacc[s][t] = fz;

        #pragma unroll
        for (int ks = 0; ks < 4; ++ks) {
            #pragma unroll
            for (int t = 0; t < 4; ++t) {
                const int row = t * 16 + ln;
                const int off = row * 256 + (((ks * 64) + g * 16) ^ ((row & 7) << 4));
                const bf16x8 kbh = *reinterpret_cast<const bf16x8*>((char*)sKhi + off);
                const bf16x8 kbl = *reinterpret_cast<const bf16x8*>((char*)sKlo + off);
                #pragma unroll
                for (int s = 0; s < 2; ++s) {
                    sacc[s][t] = __builtin_amdgcn_mfma_f32_16x16x32_bf16(qa_hi[s][ks], kbh, sacc[s][t], 0, 0, 0);
                    sacc[s][t] = __builtin_amdgcn_mfma_f32_16x16x32_bf16(qa_lo[s][ks], kbh, sacc[s][t], 0, 0, 0);
                    sacc[s][t] = __builtin_amdgcn_mfma_f32_16x16x32_bf16(qa_hi[s][ks], kbl, sacc[s][t], 0, 0, 0);
                }
            }
        }

        float dv[2][4][4];
        #pragma unroll
        for (int s = 0; s < 2; ++s)
            #pragma unroll
            for (int r = 0; r < 4; ++r) {
                const size_t drow = ((size_t)b * NN + q0 + w * 32 + s * 16 + g * 4 + r) * NN + k0;
                #pragma unroll
                for (int t = 0; t < 4; ++t) dv[s][t][r] = dist[drow + t * 16 + ln];
            }
        __syncthreads();

        #pragma unroll
        for (int s = 0; s < 2; ++s) {
            float alpha[4], mn[4];
            #pragma unroll
            for (int r = 0; r < 4; ++r) {
                float sv[4];
                #pragma unroll
                for (int t = 0; t < 4; ++t) {
                    const bool live = (mq[s][r] != 0.f) && (mk[t] != 0.f);
                    sv[t] = live ? fmaf(sacc[s][t][r], QSCALE, dv[s][t][r]) : NEGV;
                    sacc[s][t][r] = sv[t];
                }
                float tm = fmaxf(fmaxf(sv[0], sv[1]), fmaxf(sv[2], sv[3]));
                tm = fmaxf(tm, __shfl_xor(tm, 1));
                tm = fmaxf(tm, __shfl_xor(tm, 2));
                tm = fmaxf(tm, __shfl_xor(tm, 4));
                tm = fmaxf(tm, __shfl_xor(tm, 8));
                const float m2 = fmaxf(mrun[s][r], tm);
                alpha[r] = __expf(mrun[s][r] - m2);
                mrun[s][r] = m2; mn[r] = m2;
            }
            #pragma unroll
            for (int r = 0; r < 4; ++r) {
                float p[4], rs = 0.f;
                #pragma unroll
                for (int t = 0; t < 4; ++t) { p[t] = __expf(sacc[s][t][r] - mn[r]); rs += p[t]; }
                rs += __shfl_xor(rs, 1); rs += __shfl_xor(rs, 2);
                rs += __shfl_xor(rs, 4); rs += __shfl_xor(rs, 8);
                lrun[s][r] = lrun[s][r] * alpha[r] + rs;
                const int q = w * 32 + s * 16 + g * 4 + r;
                #pragma unroll
                for (int t = 0; t < 4; ++t) {
                    unsigned short ph, pl;
                    split2(p[t], ph, pl);
                    const int k = t * 16 + ln;
                    const int off = q * 256 + ((k * 4) ^ ((q & 7) << 4));
                    *reinterpret_cast<unsigned*>((char*)sP + off) = ((unsigned)ph << 16) | pl;
                }
                #pragma unroll
                for (int et = 0; et < 8; ++et) yacc[s][et][r] *= alpha[r];
            }
        }
        __syncthreads();

        #pragma unroll
        for (int ks = 0; ks < 2; ++ks) {
            bf16x8 pah[2], pal[2];
            #pragma unroll
            for (int s = 0; s < 2; ++s) {
                const int q = w * 32 + s * 16 + ln;
                const int swz = (q & 7) << 4;
                const int colb = ks * 128 + g * 32;
                const uint4 r0 = *reinterpret_cast<const uint4*>((char*)sP + q * 256 + (colb ^ swz));
                const uint4 r1 = *reinterpret_cast<const uint4*>((char*)sP + q * 256 + ((colb + 16) ^ swz));
                const unsigned wrd[8] = {r0.x, r0.y, r0.z, r0.w, r1.x, r1.y, r1.z, r1.w};
                unsigned hh[4], llw[4];
                #pragma unroll
                for (int d = 0; d < 4; ++d) {
                    hh[d]  = __builtin_amdgcn_perm(wrd[2 * d + 1], wrd[2 * d], 0x07060302u);
                    llw[d] = __builtin_amdgcn_perm(wrd[2 * d + 1], wrd[2 * d], 0x05040100u);
                }
                u32x4 th = {hh[0], hh[1], hh[2], hh[3]};
                u32x4 tl = {llw[0], llw[1], llw[2], llw[3]};
                pah[s] = __builtin_bit_cast(bf16x8, th);
                pal[s] = __builtin_bit_cast(bf16x8, tl);
            }
            #pragma unroll
            for (int et = 0; et < 8; ++et) {
                const int e = et * 16 + ln;
                const int off = e * 128 + (((ks * 64) + g * 16) ^ ((e & 7) << 4));
                const bf16x8 vbh = *reinterpret_cast<const bf16x8*>((char*)sVhi + off);
                const bf16x8 vbl = *reinterpret_cast<const bf16x8*>((char*)sVlo + off);
                #pragma unroll
                for (int s = 0; s < 2; ++s) {
                    yacc[s][et] = __builtin_amdgcn_mfma_f32_16x16x32_bf16(pah[s], vbh, yacc[s][et], 0, 0, 0);
                    yacc[s][et] = __builtin_amdgcn_mfma_f32_16x16x32_bf16(pal[s], vbh, yacc[s][et], 0, 0, 0);
                    yacc[s][et] = __builtin_amdgcn_mfma_f32_16x16x32_bf16(pah[s], vbl, yacc[s][et], 0, 0, 0);
                }
            }
        }
        __syncthreads();
    }

    // epilogue: y/l -> bf16 hi/lo at [b*512+q][h*128+e]
    #pragma unroll
    for (int s = 0; s < 2; ++s) {
        float inv[4];
        #pragma unroll
        for (int r = 0; r < 4; ++r) inv[r] = 1.0f / lrun[s][r];
        #pragma unroll
        for (int et = 0; et < 8; ++et) {
            #pragma unroll
            for (int r = 0; r < 4; ++r) {
                const int q = q0 + w * 32 + s * 16 + g * 4 + r;
                const size_t o = ((size_t)(b * NN + q)) * HE + h * EE + et * 16 + ln;
                unsigned short th, tl;
                split2(yacc[s][et][r] * inv[r], th, tl);
                Yhi[o] = th; Ylo[o] = tl;
            }
        }
    }
}

// ---------------------------------------------------------------------------
// k_out: 3-term split MFMA. M=8192, C=128, K=1024. m-tile 32, 256 blocks,
// wave = 32-col quarter. Frags straight from global (4 lanes share each 64B line).
// ---------------------------------------------------------------------------
__global__ __launch_bounds__(256) void k_out(
    const unsigned short* __restrict__ Yhi, const unsigned short* __restrict__ Ylo,
    const unsigned short* __restrict__ wohi, const unsigned short* __restrict__ wolo,
    const float* __restrict__ bo, const float* __restrict__ mask,
    float* __restrict__ out)
{
    const int tid = threadIdx.x;
    const int w = tid >> 6, l = tid & 63, g = l >> 4, ln = l & 15;
    const int m0 = blockIdx.x * 32;
    const int cq = w * 32;

    f32x4 acc[2][2];
    const f32x4 fz = {0.f, 0.f, 0.f, 0.f};
    acc[0][0] = fz; acc[0][1] = fz; acc[1][0] = fz; acc[1][1] = fz;

    #pragma unroll 4
    for (int ks = 0; ks < 32; ++ks) {
        bf16x8 ah[2], al[2], bh[2], bl[2];
        #pragma unroll
        for (int im = 0; im < 2; ++im) {
            const size_t a = (size_t)(m0 + im * 16 + ln) * HE + ks * 32 + g * 8;
            ah[im] = *reinterpret_cast<const bf16x8*>(Yhi + a);
            al[im] = *reinterpret_cast<const bf16x8*>(Ylo + a);
        }
        #pragma unroll
        for (int jc = 0; jc < 2; ++jc) {
            const size_t a = (size_t)(cq + jc * 16 + ln) * HE + ks * 32 + g * 8;
            bh[jc] = *reinterpret_cast<const bf16x8*>(wohi + a);
            bl[jc] = *reinterpret_cast<const bf16x8*>(wolo + a);
        }
        #pragma unroll
        for (int im = 0; im < 2; ++im)
            #pragma unroll
            for (int jc = 0; jc < 2; ++jc) {
                acc[im][jc] = __builtin_amdgcn_mfma_f32_16x16x32_bf16(ah[im], bl[jc], acc[im][jc], 0, 0, 0);
                acc[im][jc] = __builtin_amdgcn_mfma_f32_16x16x32_bf16(al[im], bh[jc], acc[im][jc], 0, 0, 0);
                acc[im][jc] = __builtin_amdgcn_mfma_f32_16x16x32_bf16(ah[im], bh[jc], acc[im][jc], 0, 0, 0);
            }
    }

    #pragma unroll
    for (int jc = 0; jc < 2; ++jc) {
        const int c = cq + jc * 16 + ln;
        const float bc = bo[c];
        #pragma unroll
        for (int im = 0; im < 2; ++im)
            #pragma unroll
            for (int r = 0; r < 4; ++r) {
                const int m = m0 + im * 16 + g * 4 + r;
                const int b = m >> 9, n = m & (NN - 1);
                out[(size_t)m * EE + c] = (acc[im][jc][r] + bc) * mask[b * NN + n];
            }
    }
}

// ---------------------------------------------------------------------------
extern "C" void kernel_launch(void* const* d_in, const int* in_sizes, int n_in,
                              void* d_out, int out_size, void* d_ws, size_t ws_size,
                              hipStream_t stream) {
    const float* x    = (const float*)d_in[0];
    const float* dist = (const float*)d_in[1];
    const float* mask = (const float*)d_in[2];
    const float* Wq   = (const float*)d_in[3];
    const float* bq   = (const float*)d_in[4];
    const float* Wk   = (const float*)d_in[5];
    const float* bk   = (const float*)d_in[6];
    const float* Wv   = (const float*)d_in[7];
    const float* bv   = (const float*)d_in[8];
    const float* Wo   = (const float*)d_in[9];
    const float* bo   = (const float*)d_in[10];
    float* out = (float*)d_out;

    const size_t SZ = (size_t)BB * HH * NN * EE;     // 8,388,608 elems
    if (ws_size < SZ * 16) return;                   // 134,217,728 B (same as before)
    char* ws = (char*)d_ws;
    // [0, 100.66MB): QKV splits (6 arrays x 16,777,216 B)
    unsigned short* Qhi  = (unsigned short*)(ws);
    unsigned short* Qlo  = (unsigned short*)(ws + 1 * 16777216);
    unsigned short* Khi  = (unsigned short*)(ws + 2 * 16777216);
    unsigned short* Klo  = (unsigned short*)(ws + 3 * 16777216);
    unsigned short* VThi = (unsigned short*)(ws + 4 * 16777216);
    unsigned short* VTlo = (unsigned short*)(ws + 5 * 16777216);
    // [100.66MB, 134.2MB): Y splits; x/wc splits overlap (dead once k_attn runs)
    char* yreg = ws + 6 * 16777216;
    unsigned short* Yhi  = (unsigned short*)(yreg);
    unsigned short* Ylo  = (unsigned short*)(yreg + 16777216);
    unsigned short* xhi  = (unsigned short*)(yreg);                 // 2,097,152 B
    unsigned short* xlo  = (unsigned short*)(yreg + 2097152);
    unsigned short* wchi = (unsigned short*)(yreg + 4194304);       // 786,432 B
    unsigned short* wclo = (unsigned short*)(yreg + 4980736);       // ends 5,767,168
    // Wo splits go into dead QKV region after k_attn:
    unsigned short* wohi = (unsigned short*)(ws);
    unsigned short* wolo = (unsigned short*)(ws + 262144);

    k_split<<<1408, 256, 0, stream>>>(x, Wq, Wk, Wv, xhi, xlo, wchi, wclo);
    k_qkv<<<dim3(64, 24), 256, 0, stream>>>(xhi, xlo, wchi, wclo, bq, bk, bv,
                                            Qhi, Qlo, Khi, Klo, VThi, VTlo);
    k_attn<<<dim3(HH, NN / 128, BB), 256, 0, stream>>>(Qhi, Qlo, Khi, Klo, VThi, VTlo,
                                                       dist, mask, Yhi, Ylo);
    k_split_wo<<<128, 256, 0, stream>>>(Wo, wohi, wolo);
    k_out<<<256, 256, 0, stream>>>(Yhi, Ylo, wohi, wolo, bo, mask, out);
}